// Round 1
// baseline (4038.467 us; speedup 1.0000x reference)
//
#include <hip/hip_runtime.h>
#include <hip/hip_bf16.h>

#define CCH 512
#define BATCH 8
#define TLEN 8192

using bf16 = __hip_bfloat16;

__device__ __forceinline__ float ldF(const float* p) { return *p; }
__device__ __forceinline__ float ldF(const bf16* p)  { return __bfloat162float(*p); }
__device__ __forceinline__ void stF(float* p, float v) { *p = v; }
__device__ __forceinline__ void stF(bf16* p, float v)  { *p = __float2bfloat16(v); }

// ---------------------------------------------------------------------------
// Weight norm: w[co,:,:] = g[co] * v[co,:,:] / ||v[co,:,:]||_2   (row = 1536)
// ---------------------------------------------------------------------------
__global__ __launch_bounds__(256) void wn_kernel(const float* __restrict__ v,
                                                 const float* __restrict__ g,
                                                 float* __restrict__ wout)
{
    int co = blockIdx.x;
    const float* vr = v + (size_t)co * (CCH * 3);
    float s = 0.f;
    for (int i = threadIdx.x; i < CCH * 3; i += 256) { float xv = vr[i]; s += xv * xv; }
#pragma unroll
    for (int off = 32; off > 0; off >>= 1) s += __shfl_down(s, off);
    __shared__ float red[4];
    int lane = threadIdx.x & 63, wv = threadIdx.x >> 6;
    if (lane == 0) red[wv] = s;
    __syncthreads();
    float tot = red[0] + red[1] + red[2] + red[3];
    float scale = g[co] / sqrtf(tot);
    float* wr = wout + (size_t)co * (CCH * 3);
    for (int i = threadIdx.x; i < CCH * 3; i += 256) wr[i] = vr[i] * scale;
}

// ---------------------------------------------------------------------------
// Fused activation1d: 2x polyphase upsample (6-tap) -> snake-beta -> 12-tap
// stride-2 downsample.  Tout = Tin - 2.
//   u[j]  = sum_m upf[6*phase + m] * x[t2 + m - 2],  t2=(j+2)>>1, phase=(j+2)&1
//   s[j]  = u + (1 - cos(2*a*u)) / (2*b + 1e-9),     zero outside [0, 2*Tin-4)
//   y[t]  = sum_k f[k] * s[2t + k - 5]
// Block: 256 outputs of one (b,c) row.
// ---------------------------------------------------------------------------
template <typename TI, typename TO>
__global__ __launch_bounds__(256) void act_kernel(
    const TI* __restrict__ in, TO* __restrict__ out,
    const float* __restrict__ alpha, const float* __restrict__ beta,
    const float* __restrict__ upf, const float* __restrict__ dwf,
    int Tin, int Tout)
{
    const int TS = 256;
    __shared__ float xs[TS + 12];       // x[t0-4 .. t0+TS+7]
    __shared__ float ss[2 * TS + 12];   // s[j0 .. j0+2*TS+11], j0 = 2*t0-5
    __shared__ float p01[12];           // p0 = upf[0..5], p1 = upf[6..11]
    __shared__ float fsh[12];
    int tid = threadIdx.x;
    int row = blockIdx.y;               // b*C + c
    int c = row & (CCH - 1);
    int t0 = blockIdx.x * TS;
    const TI* xr = in + (size_t)row * Tin;

    if (tid < 12) { p01[tid] = upf[tid]; fsh[tid] = dwf[tid]; }
    for (int i = tid; i < TS + 12; i += 256) {
        int xi = t0 - 4 + i;
        xs[i] = (xi >= 0 && xi < Tin) ? ldF(xr + xi) : 0.f;
    }
    __syncthreads();

    float a     = expf(alpha[c]);
    float inv2b = 1.f / (2.f * expf(beta[c]) + 1e-9f);
    float twoa  = 2.f * a;
    int Ls = 2 * Tin - 4;
    int j0 = 2 * t0 - 5;
    for (int i = tid; i < 2 * TS + 12; i += 256) {
        int j = j0 + i;
        float sv = 0.f;
        if (j >= 0 && j < Ls) {
            int t2 = (j + 2) >> 1;
            const float* ph = p01 + 6 * ((j + 2) & 1);
            int base = t2 + 2 - t0;     // xs index of x[t2-2]
            float u = 0.f;
#pragma unroll
            for (int m = 0; m < 6; ++m) u += ph[m] * xs[base + m];
            sv = u + (1.f - cosf(twoa * u)) * inv2b;
        }
        ss[i] = sv;
    }
    __syncthreads();

    int t = t0 + tid;
    if (t < Tout) {
        float y = 0.f;
#pragma unroll
        for (int k = 0; k < 12; ++k) y += fsh[k] * ss[2 * tid + k];
        stF(out + (size_t)row * Tout + t, y);
    }
}

// ---------------------------------------------------------------------------
// Dense conv1d, kernel 3, pad 1: out[b,co,t] = bias[co]
//      + sum_{ci,k} w[co,ci,k] * in[b,ci,t-1+k]   (+ res[b,co,t])
// GEMM-style tiling: 64 co x 64 t per block, KC=16 ci chunk in LDS,
// 4x4 microtile per thread (16x16 thread grid).
// ---------------------------------------------------------------------------
template <typename TI, typename TO, bool HASRES>
__global__ __launch_bounds__(256) void conv_kernel(
    const TI* __restrict__ in, const float* __restrict__ w,
    const float* __restrict__ bias, const float* __restrict__ res, int resStride,
    TO* __restrict__ out, int Tin)
{
    const int KC = 16;
    __shared__ float wsh[KC][196];      // [ci][co*3+k], padded 192->196
    __shared__ float ish[KC][72];       // [ci][t0-1 .. t0+64], padded 66->72
    int tid = threadIdx.x;
    int tx = tid & 15;                  // t groups
    int ty = tid >> 4;                  // co groups
    int t0  = blockIdx.x * 64;
    int co0 = blockIdx.y * 64;
    int b   = blockIdx.z;
    const TI* inb = in + (size_t)b * CCH * Tin;
    float acc[4][4] = {};

    for (int ci0 = 0; ci0 < CCH; ci0 += KC) {
        for (int idx = tid; idx < 64 * KC * 3; idx += 256) {
            int co = idx / (KC * 3);
            int r  = idx - co * (KC * 3);          // r = ciL*3 + k
            wsh[r / 3][co * 3 + (r % 3)] =
                w[(size_t)(co0 + co) * (CCH * 3) + (size_t)ci0 * 3 + r];
        }
        for (int idx = tid; idx < KC * 66; idx += 256) {
            int ci = idx / 66;
            int tt = idx - ci * 66;
            int t = t0 - 1 + tt;
            ish[ci][tt] = (t >= 0 && t < Tin)
                              ? ldF(inb + (size_t)(ci0 + ci) * Tin + t) : 0.f;
        }
        __syncthreads();
        for (int ciL = 0; ciL < KC; ++ciL) {
            float bv[6];
#pragma unroll
            for (int j = 0; j < 6; ++j) bv[j] = ish[ciL][tx * 4 + j];
            float av[12];
#pragma unroll
            for (int i = 0; i < 12; ++i) av[i] = wsh[ciL][ty * 12 + i];
#pragma unroll
            for (int i = 0; i < 4; ++i)
#pragma unroll
                for (int k = 0; k < 3; ++k) {
                    float aa = av[i * 3 + k];
#pragma unroll
                    for (int j = 0; j < 4; ++j) acc[i][j] += aa * bv[j + k];
                }
        }
        __syncthreads();
    }

    for (int i = 0; i < 4; ++i) {
        int co = co0 + ty * 4 + i;
        float bb = bias[co];
        TO* orow = out + ((size_t)b * CCH + co) * Tin;
        const float* rrow = HASRES ? res + ((size_t)b * CCH + co) * resStride : nullptr;
#pragma unroll
        for (int j = 0; j < 4; ++j) {
            int t = t0 + tx * 4 + j;
            if (t < Tin) {
                float v = acc[i][j] + bb;
                if (HASRES) v += rrow[t];
                stF(orow + t, v);
            }
        }
    }
}

// ---------------------------------------------------------------------------
extern "C" void kernel_launch(void* const* d_in, const int* in_sizes, int n_in,
                              void* d_out, int out_size, void* d_ws, size_t ws_size,
                              hipStream_t stream)
{
    const float* x      = (const float*)d_in[0];
    const float* alpha1 = (const float*)d_in[1];
    const float* beta1  = (const float*)d_in[2];
    const float* alpha2 = (const float*)d_in[3];
    const float* beta2  = (const float*)d_in[4];
    const float* v1     = (const float*)d_in[5];
    const float* g1     = (const float*)d_in[6];
    const float* b1     = (const float*)d_in[7];
    const float* v2     = (const float*)d_in[8];
    const float* g2     = (const float*)d_in[9];
    const float* b2     = (const float*)d_in[10];
    const float* upf    = (const float*)d_in[11];
    const float* dwf    = (const float*)d_in[12];
    float* out = (float*)d_out;

    const int T1 = TLEN - 2;  // 8190 after activation1d #1
    const int T2 = TLEN - 4;  // 8188 after activation1d #2

    // Workspace layout: w1n (fp32, 3MB) | w2n (fp32, 3MB) | bufA (bf16) | bufB (bf16)
    // Total ~140.5 MB.
    char* wsb = (char*)d_ws;
    float* w1n = (float*)wsb;
    float* w2n = w1n + (size_t)CCH * CCH * 3;
    bf16* bufA = (bf16*)(wsb + (size_t)2 * CCH * CCH * 3 * sizeof(float));
    bf16* bufB = bufA + (size_t)BATCH * CCH * T1;

    wn_kernel<<<CCH, 256, 0, stream>>>(v1, g1, w1n);
    wn_kernel<<<CCH, 256, 0, stream>>>(v2, g2, w2n);

    // act1: x (fp32, 8192) -> bufA (bf16, 8190)
    act_kernel<float, bf16><<<dim3((T1 + 255) / 256, BATCH * CCH), 256, 0, stream>>>(
        x, bufA, alpha1, beta1, upf, dwf, TLEN, T1);

    // conv1: bufA -> bufB (bf16, 8190), + b1
    conv_kernel<bf16, bf16, false><<<dim3((T1 + 63) / 64, CCH / 64, BATCH), 256, 0, stream>>>(
        bufA, w1n, b1, nullptr, 0, bufB, T1);

    // act2: bufB (8190) -> bufA (bf16, 8188)
    act_kernel<bf16, bf16><<<dim3((T2 + 255) / 256, BATCH * CCH), 256, 0, stream>>>(
        bufB, bufA, alpha2, beta2, upf, dwf, T1, T2);

    // conv2: bufA (8188) -> out (fp32), + b2 + residual x[..., :T2]
    conv_kernel<bf16, float, true><<<dim3((T2 + 63) / 64, CCH / 64, BATCH), 256, 0, stream>>>(
        bufA, w2n, b2, x, TLEN, out, T2);
}

// Round 2
// 766.964 us; speedup vs baseline: 5.2655x; 5.2655x over previous
//
#include <hip/hip_runtime.h>
#include <hip/hip_bf16.h>

#define CCH 512
#define BATCH 8
#define TLEN 8192
#define RPITCH ((size_t)TLEN * CCH)   // rows pitch per batch for t-major bf16 bufs

using f32x4 = __attribute__((ext_vector_type(4))) float;
using s16x8 = __attribute__((ext_vector_type(8))) short;
using s16x4 = __attribute__((ext_vector_type(4))) short;

__device__ __forceinline__ float b2f(short s) {
    union { unsigned int i; float f; } u; u.i = ((unsigned int)(unsigned short)s) << 16; return u.f;
}
__device__ __forceinline__ short f2b(float f) {
    __hip_bfloat16 h = __float2bfloat16(f);
    return *reinterpret_cast<short*>(&h);
}

__device__ __forceinline__ void glds16(const void* g, void* l) {
    __builtin_amdgcn_global_load_lds(
        (const __attribute__((address_space(1))) unsigned int*)g,
        (__attribute__((address_space(3))) unsigned int*)l, 16, 0, 0);
}

// ---------------------------------------------------------------------------
// Weight norm + bf16 pack into chunk-major MFMA layout:
// dest[((ci>>5)*4 + (co>>7))*3 + tap][co&127][ci&31]  (each [3][128][32] block
// = 24576 B contiguous, consumed whole by one conv block per K-chunk).
// ---------------------------------------------------------------------------
__global__ __launch_bounds__(256) void wn_pack_kernel(const float* __restrict__ v,
                                                      const float* __restrict__ g,
                                                      short* __restrict__ wp)
{
    int co = blockIdx.x;
    const float* vr = v + (size_t)co * (CCH * 3);
    float s = 0.f;
    for (int i = threadIdx.x; i < CCH * 3; i += 256) { float xv = vr[i]; s += xv * xv; }
#pragma unroll
    for (int off = 32; off > 0; off >>= 1) s += __shfl_down(s, off);
    __shared__ float red[4];
    int lane = threadIdx.x & 63, wv = threadIdx.x >> 6;
    if (lane == 0) red[wv] = s;
    __syncthreads();
    float tot = red[0] + red[1] + red[2] + red[3];
    float scale = g[co] / sqrtf(tot);
    for (int i = threadIdx.x; i < CCH * 3; i += 256) {
        int ci = i / 3, tap = i - ci * 3;
        size_t dst = ((size_t)(((ci >> 5) * 4 + (co >> 7)) * 3 + tap)) * 4096
                     + (size_t)(co & 127) * 32 + (ci & 31);
        wp[dst] = f2b(vr[i] * scale);
    }
}

// ---------------------------------------------------------------------------
// Transpose x fp32 [b][c][8192] -> bf16 t-major [b][8192][512]
// ---------------------------------------------------------------------------
__global__ __launch_bounds__(256) void transpose_kernel(const float* __restrict__ x,
                                                        short* __restrict__ out)
{
    __shared__ float ls[64][65];
    int tid = threadIdx.x;
    int t0 = blockIdx.x * 64, c0 = blockIdx.y * 64, b = blockIdx.z;
    const float* xb = x + (size_t)b * CCH * TLEN;
#pragma unroll
    for (int p = 0; p < 4; ++p) {
        int c = p * 16 + (tid >> 4);
        int t4 = (tid & 15) * 4;
        f32x4 v = *(const f32x4*)&xb[(size_t)(c0 + c) * TLEN + t0 + t4];
#pragma unroll
        for (int i = 0; i < 4; ++i) ls[c][t4 + i] = v[i];
    }
    __syncthreads();
    short* ob = out + (size_t)b * RPITCH;
#pragma unroll
    for (int p = 0; p < 16; ++p) {
        int idx = p * 256 + tid;
        int t = idx >> 6, c = idx & 63;
        ob[(size_t)(t0 + t) * CCH + c0 + c] = f2b(ls[c][t]);
    }
}

// ---------------------------------------------------------------------------
// Fused activation1d on t-major layout. lane = channel, sliding window in t.
//   s[j] = snake(sum_m upf[6*phase+m] * x[t2-2+m]),  t2=(j+2)>>1, phase=(j+2)&1
//   y[t] = sum_k dwf[k] * s[2t-5+k]
// ---------------------------------------------------------------------------
#define ALT 256
__global__ __launch_bounds__(256) void act_kernel(
    const short* __restrict__ in, short* __restrict__ out,
    const float* __restrict__ alpha, const float* __restrict__ beta,
    const float* __restrict__ upf, const float* __restrict__ dwf,
    int Tin, int Tout)
{
    int tid = threadIdx.x;
    int c = blockIdx.y * 256 + tid;
    int b = blockIdx.z;
    int t0 = blockIdx.x * ALT;
    const short* ib = in + (size_t)b * RPITCH;
    short* ob = out + (size_t)b * RPITCH;

    float ph0[6], ph1[6], fw[12];
#pragma unroll
    for (int m = 0; m < 6; ++m) { ph0[m] = upf[m]; ph1[m] = upf[6 + m]; }
#pragma unroll
    for (int k = 0; k < 12; ++k) fw[k] = dwf[k];

    float a     = __expf(alpha[c]);
    float inv2b = 1.f / (2.f * __expf(beta[c]) + 1e-9f);
    float twoa  = 2.f * a;
    int Ls = 2 * Tin - 4;

    auto ldx = [&](int t) -> float {
        return (t >= 0 && t < Tin) ? b2f(ib[(size_t)t * CCH + c]) : 0.f;
    };
    auto snake = [&](float u) -> float {
        return u + (1.f - __cosf(twoa * u)) * inv2b;
    };

    // warm-up: xa = x[t0-4 .. t0+7]; sr[i] = s[2*t0-5+i]
    float xa[12];
#pragma unroll
    for (int i = 0; i < 12; ++i) xa[i] = ldx(t0 - 4 + i);
    float sr[12];
#pragma unroll
    for (int i = 0; i < 12; ++i) {
        int j = 2 * t0 - 5 + i;
        int xoff = ((i - 3) >> 1) + 2;       // static per i
        const float* ph = ((i + 1) & 1) ? ph1 : ph0;
        float u = 0.f;
#pragma unroll
        for (int m = 0; m < 6; ++m) u += ph[m] * xa[xoff + m];
        sr[i] = (j >= 0 && j < Ls) ? snake(u) : 0.f;
    }
    float xw[7];
#pragma unroll
    for (int m = 0; m < 6; ++m) xw[m] = xa[6 + m];
    xw[6] = ldx(t0 + 8);

#pragma unroll 4
    for (int it = 0; it < ALT; ++it) {
        int t = t0 + it;
        float y = 0.f;
#pragma unroll
        for (int k = 0; k < 12; ++k) y += fw[k] * sr[k];
        if (t < Tout) ob[(size_t)t * CCH + c] = f2b(y);
        // new s at j1=2t+7 (phase 1, x[t+2..t+7]) and j2=2t+8 (phase 0, x[t+3..t+8])
        float u1 = 0.f, u2 = 0.f;
#pragma unroll
        for (int m = 0; m < 6; ++m) { u1 += ph1[m] * xw[m]; u2 += ph0[m] * xw[m + 1]; }
        float s1 = (2 * t + 7 < Ls) ? snake(u1) : 0.f;
        float s2 = (2 * t + 8 < Ls) ? snake(u2) : 0.f;
#pragma unroll
        for (int i = 0; i < 10; ++i) sr[i] = sr[i + 2];
        sr[10] = s1; sr[11] = s2;
#pragma unroll
        for (int m = 0; m < 6; ++m) xw[m] = xw[m + 1];
        xw[6] = ldx(t + 9);
    }
}

// ---------------------------------------------------------------------------
// MFMA conv1d (k=3, pad=1) on t-major bf16 input.
// Block: 128co x 128t, 4 waves (2x2), wave = 64x64 = 4x4 fragments 16x16x32.
// K-loop: 16 chunks of 32 ci; 3-tap inner loop with row-shifted B fragments.
// MODE 0: out bf16 t-major (+bias). MODE 1: out fp32 [b][co][t] (+bias+residual).
// ---------------------------------------------------------------------------
template <int MODE>
__global__ __launch_bounds__(256) void conv_mfma(
    const short* __restrict__ xin, const short* __restrict__ wp,
    const float* __restrict__ bias, const float* __restrict__ resid,
    float* __restrict__ outF, short* __restrict__ outT, int rows)
{
    __shared__ __align__(16) short wlds[3 * 128 * 32];   // [tap][coL][ciL]
    __shared__ __align__(16) short ilds[132 * 32];       // row r = t0-1+r, [r][ciL]
    int tid = threadIdx.x;
    int wave = tid >> 6, lane = tid & 63;
    int quad = lane >> 4, l16 = lane & 15;
    int wm = wave >> 1, wn = wave & 1;
    int t0 = blockIdx.x * 128, cog = blockIdx.y, b = blockIdx.z;

    const short* inb = xin + (size_t)b * RPITCH;
    f32x4 acc[4][4];
#pragma unroll
    for (int i = 0; i < 4; ++i)
#pragma unroll
        for (int j = 0; j < 4; ++j) acc[i][j] = 0.f;

    bool interior = (t0 >= 1) && (t0 + 129 <= rows);

    for (int cc = 0; cc < 16; ++cc) {
        const short* wsrc = wp + (size_t)(cc * 4 + cog) * (3 * 128 * 32);
#pragma unroll
        for (int p = 0; p < 6; ++p) {
            int seg = wave * 6 + p;
            glds16(wsrc + seg * 512 + lane * 8, wlds + seg * 512);
        }
        const short* isrc = inb + (size_t)(t0 - 1) * CCH + cc * 32;
        if (interior) {
#pragma unroll
            for (int p = 0; p < 2; ++p) {
                int seg0 = (p * 4 + wave) * 64;
                int s = seg0 + lane;
                glds16(isrc + (size_t)(s >> 2) * CCH + (s & 3) * 8, ilds + seg0 * 8);
            }
            if (wave == 0 && lane < 8) {
                int s = 512 + lane;
                glds16(isrc + (size_t)(s >> 2) * CCH + (s & 3) * 8, ilds + 512 * 8);
            }
        } else {
            for (int s = tid; s < 520; s += 256) {
                int gt = t0 - 1 + (s >> 2);
                s16x8 v = 0;
                if (gt >= 0 && gt < rows)
                    v = *(const s16x8*)(inb + (size_t)gt * CCH + cc * 32 + (s & 3) * 8);
                *(s16x8*)(ilds + s * 8) = v;
            }
        }
        __syncthreads();
#pragma unroll
        for (int tap = 0; tap < 3; ++tap) {
            s16x8 af[4], bv[4];
#pragma unroll
            for (int mf = 0; mf < 4; ++mf)
                af[mf] = *(const s16x8*)(wlds + tap * 4096 + (wm * 64 + mf * 16 + l16) * 32 + quad * 8);
#pragma unroll
            for (int nf = 0; nf < 4; ++nf)
                bv[nf] = *(const s16x8*)(ilds + (wn * 64 + nf * 16 + l16 + tap) * 32 + quad * 8);
#pragma unroll
            for (int mf = 0; mf < 4; ++mf)
#pragma unroll
                for (int nf = 0; nf < 4; ++nf)
                    acc[mf][nf] = __builtin_amdgcn_mfma_f32_16x16x32_bf16(
                        af[mf], bv[nf], acc[mf][nf], 0, 0, 0);
        }
        __syncthreads();
    }

    f32x4 b4[4];
#pragma unroll
    for (int mf = 0; mf < 4; ++mf)
        b4[mf] = *(const f32x4*)(bias + cog * 128 + wm * 64 + mf * 16 + quad * 4);

#pragma unroll
    for (int mf = 0; mf < 4; ++mf) {
#pragma unroll
        for (int nf = 0; nf < 4; ++nf) {
            int t = t0 + wn * 64 + nf * 16 + l16;
            if (t >= rows) continue;
            if (MODE == 0) {
                int co = cog * 128 + wm * 64 + mf * 16 + quad * 4;
                s16x4 o;
#pragma unroll
                for (int r = 0; r < 4; ++r) o[r] = f2b(acc[mf][nf][r] + b4[mf][r]);
                *(s16x4*)(outT + (size_t)b * RPITCH + (size_t)t * CCH + co) = o;
            } else {
#pragma unroll
                for (int r = 0; r < 4; ++r) {
                    int co = cog * 128 + wm * 64 + mf * 16 + quad * 4 + r;
                    size_t rb = (size_t)b * CCH + co;
                    outF[rb * (size_t)rows + t] =
                        acc[mf][nf][r] + b4[mf][r] + resid[rb * (size_t)TLEN + t];
                }
            }
        }
    }
}

// ---------------------------------------------------------------------------
extern "C" void kernel_launch(void* const* d_in, const int* in_sizes, int n_in,
                              void* d_out, int out_size, void* d_ws, size_t ws_size,
                              hipStream_t stream)
{
    const float* x      = (const float*)d_in[0];
    const float* alpha1 = (const float*)d_in[1];
    const float* beta1  = (const float*)d_in[2];
    const float* alpha2 = (const float*)d_in[3];
    const float* beta2  = (const float*)d_in[4];
    const float* v1     = (const float*)d_in[5];
    const float* g1     = (const float*)d_in[6];
    const float* b1     = (const float*)d_in[7];
    const float* v2     = (const float*)d_in[8];
    const float* g2     = (const float*)d_in[9];
    const float* b2     = (const float*)d_in[10];
    const float* upf    = (const float*)d_in[11];
    const float* dwf    = (const float*)d_in[12];
    float* out = (float*)d_out;

    const int T1 = TLEN - 2;  // 8190
    const int T2 = TLEN - 4;  // 8188

    // ws: w1p | w2p (bf16 packed, 1.5 MB each) | bufX | bufY (bf16, 67.1 MB each)
    char* wsb = (char*)d_ws;
    short* w1p = (short*)wsb;
    short* w2p = w1p + (size_t)CCH * CCH * 3;
    short* bufX = w2p + (size_t)CCH * CCH * 3;
    short* bufY = bufX + (size_t)BATCH * RPITCH;

    wn_pack_kernel<<<CCH, 256, 0, stream>>>(v1, g1, w1p);
    wn_pack_kernel<<<CCH, 256, 0, stream>>>(v2, g2, w2p);

    transpose_kernel<<<dim3(TLEN / 64, CCH / 64, BATCH), 256, 0, stream>>>(x, bufX);

    act_kernel<<<dim3((T1 + ALT - 1) / ALT, CCH / 256, BATCH), 256, 0, stream>>>(
        bufX, bufY, alpha1, beta1, upf, dwf, TLEN, T1);

    conv_mfma<0><<<dim3((T1 + 127) / 128, 4, BATCH), 256, 0, stream>>>(
        bufY, w1p, b1, nullptr, nullptr, bufX, T1);

    act_kernel<<<dim3((T2 + ALT - 1) / ALT, CCH / 256, BATCH), 256, 0, stream>>>(
        bufX, bufY, alpha2, beta2, upf, dwf, T1, T2);

    conv_mfma<1><<<dim3((T2 + 127) / 128, 4, BATCH), 256, 0, stream>>>(
        bufY, w2p, b2, x, out, nullptr, T2);
}

// Round 3
// 678.403 us; speedup vs baseline: 5.9529x; 1.1305x over previous
//
#include <hip/hip_runtime.h>
#include <hip/hip_bf16.h>

#define CCH 512
#define BATCH 8
#define TLEN 8192
#define RPITCH ((size_t)TLEN * CCH)   // per-batch pitch for t-major bf16 bufs

using f32x4 = __attribute__((ext_vector_type(4))) float;
using s16x8 = __attribute__((ext_vector_type(8))) short;
using s16x4 = __attribute__((ext_vector_type(4))) short;
using s16x2 = __attribute__((ext_vector_type(2))) short;

__device__ __forceinline__ float b2f(short s) {
    union { unsigned int i; float f; } u; u.i = ((unsigned int)(unsigned short)s) << 16; return u.f;
}
__device__ __forceinline__ short f2b(float f) {
    __hip_bfloat16 h = __float2bfloat16(f);
    return *reinterpret_cast<short*>(&h);
}

__device__ __forceinline__ void glds16(const void* g, void* l) {
    __builtin_amdgcn_global_load_lds(
        (const __attribute__((address_space(1))) unsigned int*)g,
        (__attribute__((address_space(3))) unsigned int*)l, 16, 0, 0);
}

// ---------------------------------------------------------------------------
// Weight norm + bf16 pack into chunk-major MFMA layout:
// dest[((ci>>5)*4 + (co>>7))*3 + tap][co&127][ci&31]
// ---------------------------------------------------------------------------
__global__ __launch_bounds__(256) void wn_pack_kernel(const float* __restrict__ v,
                                                      const float* __restrict__ g,
                                                      short* __restrict__ wp)
{
    int co = blockIdx.x;
    const float* vr = v + (size_t)co * (CCH * 3);
    float s = 0.f;
    for (int i = threadIdx.x; i < CCH * 3; i += 256) { float xv = vr[i]; s += xv * xv; }
#pragma unroll
    for (int off = 32; off > 0; off >>= 1) s += __shfl_down(s, off);
    __shared__ float red[4];
    int lane = threadIdx.x & 63, wv = threadIdx.x >> 6;
    if (lane == 0) red[wv] = s;
    __syncthreads();
    float tot = red[0] + red[1] + red[2] + red[3];
    float scale = g[co] / sqrtf(tot);
    for (int i = threadIdx.x; i < CCH * 3; i += 256) {
        int ci = i / 3, tap = i - ci * 3;
        size_t dst = ((size_t)(((ci >> 5) * 4 + (co >> 7)) * 3 + tap)) * 4096
                     + (size_t)(co & 127) * 32 + (ci & 31);
        wp[dst] = f2b(vr[i] * scale);
    }
}

// ---------------------------------------------------------------------------
// Transpose x fp32 [b][c][8192] -> bf16 t-major [b][8192][512]
// ---------------------------------------------------------------------------
__global__ __launch_bounds__(256) void transpose_kernel(const float* __restrict__ x,
                                                        short* __restrict__ out)
{
    __shared__ float ls[64][65];
    int tid = threadIdx.x;
    int t0 = blockIdx.x * 64, c0 = blockIdx.y * 64, b = blockIdx.z;
    const float* xb = x + (size_t)b * CCH * TLEN;
#pragma unroll
    for (int p = 0; p < 4; ++p) {
        int c = p * 16 + (tid >> 4);
        int t4 = (tid & 15) * 4;
        f32x4 v = *(const f32x4*)&xb[(size_t)(c0 + c) * TLEN + t0 + t4];
#pragma unroll
        for (int i = 0; i < 4; ++i) ls[c][t4 + i] = v[i];
    }
    __syncthreads();
    short* ob = out + (size_t)b * RPITCH;
#pragma unroll
    for (int p = 0; p < 4; ++p) {
        int t = p * 16 + (tid >> 4);
        int c4 = (tid & 15) * 4;
        s16x4 o;
#pragma unroll
        for (int i = 0; i < 4; ++i) o[i] = f2b(ls[c4 + i][t]);
        *(s16x4*)(ob + (size_t)(t0 + t) * CCH + c0 + c4) = o;
#pragma unroll
        for (int q = 1; q < 4; ++q) {
            int t2 = p * 16 + (tid >> 4) + q * 0; // placeholder to keep structure simple
        }
    }
    // remaining 48 t-rows
#pragma unroll
    for (int p = 4; p < 16; ++p) {
        int t = (p - 4) * 16 + 16 + (tid >> 4) + ((p - 4) / 3) * 0;
        (void)t;
        break;
    }
    // NOTE: simpler complete loop (overwrites nothing wrong): do all 64 rows
#pragma unroll
    for (int p = 0; p < 4; ++p) {
        int base_t = p * 16 + (tid >> 4);
        int c4 = (tid & 15) * 4;
        (void)base_t; (void)c4;
    }
    __syncthreads();
}

// The transpose above got tangled; use a clean dedicated kernel instead.
__global__ __launch_bounds__(256) void transpose_kernel2(const float* __restrict__ x,
                                                         short* __restrict__ out)
{
    __shared__ float ls[64][65];
    int tid = threadIdx.x;
    int t0 = blockIdx.x * 64, c0 = blockIdx.y * 64, b = blockIdx.z;
    const float* xb = x + (size_t)b * CCH * TLEN;
#pragma unroll
    for (int p = 0; p < 4; ++p) {
        int c = p * 16 + (tid >> 4);
        int t4 = (tid & 15) * 4;
        f32x4 v = *(const f32x4*)&xb[(size_t)(c0 + c) * TLEN + t0 + t4];
#pragma unroll
        for (int i = 0; i < 4; ++i) ls[c][t4 + i] = v[i];
    }
    __syncthreads();
    short* ob = out + (size_t)b * RPITCH;
#pragma unroll
    for (int p = 0; p < 4; ++p) {
        int t = p * 16 + (tid >> 4);
        int c4 = (tid & 15) * 4;
        s16x4 o;
#pragma unroll
        for (int i = 0; i < 4; ++i) o[i] = f2b(ls[c4 + i][t]);
        *(s16x4*)(ob + (size_t)(t0 + t) * CCH + c0 + c4) = o;
    }
}

// ---------------------------------------------------------------------------
// Fused activation1d on t-major layout; 2 channels per lane, 256 threads
// cover all 512 channels.  ALT=128 outputs per block along t.
// ---------------------------------------------------------------------------
#define ALT 128
__global__ __launch_bounds__(256) void act_kernel(
    const short* __restrict__ in, short* __restrict__ out,
    const float* __restrict__ alpha, const float* __restrict__ beta,
    const float* __restrict__ upf, const float* __restrict__ dwf,
    int Tin, int Tout)
{
    int tid = threadIdx.x;
    int c2 = tid * 2;
    int b = blockIdx.z;
    int t0 = blockIdx.x * ALT;
    const short* ib = in + (size_t)b * RPITCH + c2;
    short* ob = out + (size_t)b * RPITCH + c2;

    float ph0[6], ph1[6], fw[12];
#pragma unroll
    for (int m = 0; m < 6; ++m) { ph0[m] = upf[m]; ph1[m] = upf[6 + m]; }
#pragma unroll
    for (int k = 0; k < 12; ++k) fw[k] = dwf[k];

    float twoa[2], inv2b[2];
#pragma unroll
    for (int ch = 0; ch < 2; ++ch) {
        twoa[ch]  = 2.f * __expf(alpha[c2 + ch]);
        inv2b[ch] = 1.f / (2.f * __expf(beta[c2 + ch]) + 1e-9f);
    }
    int Ls = 2 * Tin - 4;

    auto ldx2 = [&](int t, float* dst) {
        if (t >= 0 && t < Tin) {
            s16x2 v = *(const s16x2*)(ib + (size_t)t * CCH);
            dst[0] = b2f(v[0]); dst[1] = b2f(v[1]);
        } else { dst[0] = 0.f; dst[1] = 0.f; }
    };

    float xa[12][2];
#pragma unroll
    for (int i = 0; i < 12; ++i) ldx2(t0 - 4 + i, xa[i]);
    float sr[12][2];
#pragma unroll
    for (int i = 0; i < 12; ++i) {
        int j = 2 * t0 - 5 + i;
        int xoff = ((i - 3) >> 1) + 2;
        const float* ph = ((i + 1) & 1) ? ph1 : ph0;
        bool ok = (j >= 0 && j < Ls);
#pragma unroll
        for (int ch = 0; ch < 2; ++ch) {
            float u = 0.f;
#pragma unroll
            for (int m = 0; m < 6; ++m) u += ph[m] * xa[xoff + m][ch];
            sr[i][ch] = ok ? (u + (1.f - __cosf(twoa[ch] * u)) * inv2b[ch]) : 0.f;
        }
    }
    float xw[7][2];
#pragma unroll
    for (int m = 0; m < 6; ++m) { xw[m][0] = xa[6 + m][0]; xw[m][1] = xa[6 + m][1]; }
    ldx2(t0 + 8, xw[6]);

#pragma unroll 4
    for (int it = 0; it < ALT; ++it) {
        int t = t0 + it;
        float y[2] = {0.f, 0.f};
#pragma unroll
        for (int k = 0; k < 12; ++k) {
            y[0] += fw[k] * sr[k][0];
            y[1] += fw[k] * sr[k][1];
        }
        if (t < Tout) {
            s16x2 o; o[0] = f2b(y[0]); o[1] = f2b(y[1]);
            *(s16x2*)(ob + (size_t)t * CCH) = o;
        }
        bool ok1 = (2 * t + 7 < Ls), ok2 = (2 * t + 8 < Ls);
        float s1[2], s2[2];
#pragma unroll
        for (int ch = 0; ch < 2; ++ch) {
            float u1 = 0.f, u2 = 0.f;
#pragma unroll
            for (int m = 0; m < 6; ++m) {
                u1 += ph1[m] * xw[m][ch];
                u2 += ph0[m] * xw[m + 1][ch];
            }
            s1[ch] = ok1 ? (u1 + (1.f - __cosf(twoa[ch] * u1)) * inv2b[ch]) : 0.f;
            s2[ch] = ok2 ? (u2 + (1.f - __cosf(twoa[ch] * u2)) * inv2b[ch]) : 0.f;
        }
#pragma unroll
        for (int i = 0; i < 10; ++i) { sr[i][0] = sr[i + 2][0]; sr[i][1] = sr[i + 2][1]; }
        sr[10][0] = s1[0]; sr[10][1] = s1[1];
        sr[11][0] = s2[0]; sr[11][1] = s2[1];
#pragma unroll
        for (int m = 0; m < 6; ++m) { xw[m][0] = xw[m + 1][0]; xw[m][1] = xw[m + 1][1]; }
        ldx2(t + 9, xw[6]);
    }
}

// ---------------------------------------------------------------------------
// MFMA conv1d (k=3, pad=1) on t-major bf16 input, double-buffered LDS.
// Block: 128co x 128t, 4 waves (2x2), wave = 64x64 = 4x4 frag 16x16x32.
// Grid.x = 4*cogroups fastest: bx&3 = cog, bx>>2 = t-tile (L2 locality).
// MODE 0: out bf16 t-major (+bias). MODE 1: out fp32 [b][co][t] (+bias+res).
// Epilogues stage the tile in LDS for fully-coalesced line-covering stores.
// ---------------------------------------------------------------------------
template <int MODE>
__global__ __launch_bounds__(256) void conv_mfma(
    const short* __restrict__ xin, const short* __restrict__ wp,
    const float* __restrict__ bias, const float* __restrict__ resid,
    float* __restrict__ outF, short* __restrict__ outT, int rows)
{
    constexpr int WB = 3 * 128 * 32;   // shorts (24576 B)
    constexpr int IB = 132 * 32;       // shorts (8448 B)
    __shared__ __align__(16) short lds[2 * (WB + IB)];   // 66048 B

    int tid = threadIdx.x;
    int wave = tid >> 6, lane = tid & 63;
    int quad = lane >> 4, l16 = lane & 15;
    int wm = wave >> 1, wn = wave & 1;
    int bx = blockIdx.x;
    int cog = bx & 3, tt = bx >> 2;
    int t0 = tt * 128, b = blockIdx.z;

    const short* inb = xin + (size_t)b * RPITCH;
    bool interior = (t0 >= 1) && (t0 + 129 <= rows);

    auto stage = [&](int cc, int pb) {
        short* base = lds + pb * (WB + IB);
        short* wl = base;
        short* il = base + WB;
        const short* wsrc = wp + (size_t)(cc * 4 + cog) * WB;
#pragma unroll
        for (int p = 0; p < 6; ++p) {
            int seg = wave * 6 + p;
            glds16(wsrc + seg * 512 + lane * 8, wl + seg * 512);
        }
        const short* isrc = inb + (size_t)(t0 - 1) * CCH + cc * 32;
        if (interior) {
#pragma unroll
            for (int p = 0; p < 2; ++p) {
                int seg0 = (p * 4 + wave) * 64;
                int s = seg0 + lane;
                glds16(isrc + (size_t)(s >> 2) * CCH + (s & 3) * 8, il + seg0 * 8);
            }
            if (wave == 0 && lane < 8) {
                int s = 512 + lane;
                glds16(isrc + (size_t)(s >> 2) * CCH + (s & 3) * 8, il + 512 * 8);
            }
        } else {
            for (int s = tid; s < 520; s += 256) {
                int gt = t0 - 1 + (s >> 2);
                s16x8 v = 0;
                if (gt >= 0 && gt < rows)
                    v = *(const s16x8*)(inb + (size_t)gt * CCH + cc * 32 + (s & 3) * 8);
                *(s16x8*)(il + s * 8) = v;
            }
        }
    };

    f32x4 acc[4][4];
#pragma unroll
    for (int i = 0; i < 4; ++i)
#pragma unroll
        for (int j = 0; j < 4; ++j) acc[i][j] = 0.f;

    stage(0, 0);
    __syncthreads();

    for (int cc = 0; cc < 16; ++cc) {
        int pb = cc & 1;
        if (cc < 15) stage(cc + 1, pb ^ 1);
        const short* base = lds + pb * (WB + IB);
        const short* wl = base;
        const short* il = base + WB;
#pragma unroll
        for (int tap = 0; tap < 3; ++tap) {
            s16x8 af[4], bv[4];
#pragma unroll
            for (int mf = 0; mf < 4; ++mf)
                af[mf] = *(const s16x8*)(wl + tap * 4096 + (wm * 64 + mf * 16 + l16) * 32 + quad * 8);
#pragma unroll
            for (int nf = 0; nf < 4; ++nf)
                bv[nf] = *(const s16x8*)(il + (wn * 64 + nf * 16 + l16 + tap) * 32 + quad * 8);
#pragma unroll
            for (int mf = 0; mf < 4; ++mf)
#pragma unroll
                for (int nf = 0; nf < 4; ++nf)
                    acc[mf][nf] = __builtin_amdgcn_mfma_f32_16x16x32_bf16(
                        af[mf], bv[nf], acc[mf][nf], 0, 0, 0);
        }
        __syncthreads();
    }

    f32x4 b4[4];
#pragma unroll
    for (int mf = 0; mf < 4; ++mf)
        b4[mf] = *(const f32x4*)(bias + cog * 128 + wm * 64 + mf * 16 + quad * 4);

    if (MODE == 0) {
        // Stage bf16 tile [t 128][co 128] (pitch 136) then coalesced stores.
        short* ot = lds;
#pragma unroll
        for (int mf = 0; mf < 4; ++mf)
#pragma unroll
            for (int nf = 0; nf < 4; ++nf) {
                int t = wn * 64 + nf * 16 + l16;
                int co = wm * 64 + mf * 16 + quad * 4;
                s16x4 o;
#pragma unroll
                for (int r = 0; r < 4; ++r) o[r] = f2b(acc[mf][nf][r] + b4[mf][r]);
                *(s16x4*)(ot + t * 136 + co) = o;
            }
        __syncthreads();
#pragma unroll
        for (int rr = 0; rr < 8; ++rr) {
            int idx = rr * 256 + tid;
            int tr = idx >> 4, c8 = (idx & 15) * 8;
            int t = t0 + tr;
            if (t < rows)
                *(s16x8*)(outT + (size_t)b * RPITCH + (size_t)t * CCH + cog * 128 + c8)
                    = *(const s16x8*)(ot + tr * 136 + c8);
        }
    } else {
        // Two halves of fp32 [co 64][t 128] (pitch 132), +bias then +residual.
        float* of = (float*)lds;
#pragma unroll
        for (int h = 0; h < 2; ++h) {
            if (wm == h) {
#pragma unroll
                for (int mf = 0; mf < 4; ++mf)
#pragma unroll
                    for (int nf = 0; nf < 4; ++nf) {
                        int t = wn * 64 + nf * 16 + l16;
#pragma unroll
                        for (int r = 0; r < 4; ++r)
                            of[(mf * 16 + quad * 4 + r) * 132 + t] = acc[mf][nf][r] + b4[mf][r];
                    }
            }
            __syncthreads();
#pragma unroll
            for (int rr = 0; rr < 8; ++rr) {
                int idx = rr * 256 + tid;
                int row = idx >> 5, c4 = (idx & 31) * 4;
                int co = cog * 128 + h * 64 + row;
                int t = t0 + c4;
                f32x4 v = *(const f32x4*)(of + row * 132 + c4);
                size_t ro = (size_t)b * CCH + co;
                const float* rrow = resid + ro * TLEN;
                float* orow = outF + ro * (size_t)rows;
                if (t + 3 < rows) {
                    f32x4 rv = *(const f32x4*)(rrow + t);
                    f32x4 ov;
#pragma unroll
                    for (int i = 0; i < 4; ++i) ov[i] = v[i] + rv[i];
                    *(f32x4*)(orow + t) = ov;
                } else {
#pragma unroll
                    for (int i = 0; i < 4; ++i)
                        if (t + i < rows) orow[t + i] = v[i] + rrow[t + i];
                }
            }
            __syncthreads();
        }
    }
}

// ---------------------------------------------------------------------------
extern "C" void kernel_launch(void* const* d_in, const int* in_sizes, int n_in,
                              void* d_out, int out_size, void* d_ws, size_t ws_size,
                              hipStream_t stream)
{
    const float* x      = (const float*)d_in[0];
    const float* alpha1 = (const float*)d_in[1];
    const float* beta1  = (const float*)d_in[2];
    const float* alpha2 = (const float*)d_in[3];
    const float* beta2  = (const float*)d_in[4];
    const float* v1     = (const float*)d_in[5];
    const float* g1     = (const float*)d_in[6];
    const float* b1     = (const float*)d_in[7];
    const float* v2     = (const float*)d_in[8];
    const float* g2     = (const float*)d_in[9];
    const float* b2     = (const float*)d_in[10];
    const float* upf    = (const float*)d_in[11];
    const float* dwf    = (const float*)d_in[12];
    float* out = (float*)d_out;

    const int T1 = TLEN - 2;  // 8190
    const int T2 = TLEN - 4;  // 8188

    char* wsb = (char*)d_ws;
    short* w1p = (short*)wsb;
    short* w2p = w1p + (size_t)CCH * CCH * 3;
    short* bufX = w2p + (size_t)CCH * CCH * 3;
    short* bufY = bufX + (size_t)BATCH * RPITCH;

    wn_pack_kernel<<<CCH, 256, 0, stream>>>(v1, g1, w1p);
    wn_pack_kernel<<<CCH, 256, 0, stream>>>(v2, g2, w2p);

    transpose_kernel2<<<dim3(TLEN / 64, CCH / 64, BATCH), 256, 0, stream>>>(x, bufX);

    act_kernel<<<dim3((TLEN + ALT - 1) / ALT, 1, BATCH), 256, 0, stream>>>(
        bufX, bufY, alpha1, beta1, upf, dwf, TLEN, T1);

    conv_mfma<0><<<dim3(256, 1, BATCH), 256, 0, stream>>>(
        bufY, w1p, b1, nullptr, nullptr, bufX, T1);

    act_kernel<<<dim3((T1 + ALT - 1) / ALT, 1, BATCH), 256, 0, stream>>>(
        bufX, bufY, alpha2, beta2, upf, dwf, T1, T2);

    conv_mfma<1><<<dim3(256, 1, BATCH), 256, 0, stream>>>(
        bufY, w2p, b2, x, out, nullptr, T2);
}